// Round 12
// baseline (145.682 us; speedup 1.0000x reference)
//
#include <hip/hip_runtime.h>
#include <math.h>

#define NPOS 4096
#define DCH  512
#define HD   32
#define NH   16
#define KW   9
#define DIL  3
#define PAD  12
#define TILE   32                  // tokens per tile (one wave-iteration)
#define NTILES (NPOS / TILE)       // 128
#define TPB    4                   // tiles per persistent wave
#define NBLK   (NTILES / TPB)      // 32 blocks per bh
#define SPANT  (TILE + 2*PAD)      // 56 tokens staged per tile
#define RS     60                  // LDS row stride floats (56 + 4 pad).
                                   // cs-step stride 4*60=240 ≡ 16 mod 32 banks -> 2-way
                                   // aliasing (free); 15 chunks/row -> chunk c at float
                                   // 4c EXACTLY LINEAR (row*60+4*c4 = 4*(15*row+c4)).
#define ROWC   (RS / 4)            // 15 16B chunks per row
#define NCHK   (2 * HD * ROWC)     // 960 chunks per tile: K rows 0..31, V rows 32..63
#define NINST  (NCHK / 64)         // 15 staging insts per wave (exact, no tail)
#define CSPL   8                   // channel-split lanes per token-group
#define CPT    (HD / CSPL)         // 4 channels per thread
#define TPT    4                   // tokens per thread (8 groups x 4)
#define WSPAN  28                  // 4 tokens x 9 taps span 28 tokens
#define WCHK   (WSPAN / 4)         // 7 float4 chunks per window
#define NXCD   8

// Native clang vector for nontemporal builtin (HIP float4 is a class type).
typedef float floatx4 __attribute__((ext_vector_type(4)));

// Direct global->LDS (16B). LDS dest linear in lane (c = it*64 + lane).
__device__ __forceinline__ void gload16(const float* g, float* l) {
    __builtin_amdgcn_global_load_lds(
        (const __attribute__((address_space(1))) void*)g,
        (__attribute__((address_space(3))) void*)l,
        16, 0, 0);
}

// Butterfly sum over 8 consecutive lanes — pure VALU via DPP.
__device__ __forceinline__ float dpp_sum8(float x) {
    int t;
    t = __builtin_amdgcn_update_dpp(0, __float_as_int(x), 0xB1, 0xF, 0xF, true);
    x += __int_as_float(t);
    t = __builtin_amdgcn_update_dpp(0, __float_as_int(x), 0x4E, 0xF, 0xF, true);
    x += __int_as_float(t);
    t = __builtin_amdgcn_update_dpp(0, __float_as_int(x), 0x141, 0xF, 0xF, true);
    x += __int_as_float(t);
    return x;
}

// Stage one tile's K+V span into a private buffer: 15 x global_load_lds_dwordx4.
// Per-lane global src CLAMPED to [0, NPOS-4]: ws % 4 == 0 aligns the boundary,
// so a clamped chunk's taps are ALL invalid (their probability is exactly 0).
__device__ __forceinline__ void stage_kv(const float* kg, const float* vg,
                                         int ws, int tid, float* buf) {
#pragma unroll
    for (int it = 0; it < NINST; ++it) {
        int c   = it * 64 + tid;                 // 0..959
        int row = c / ROWC;                      // 0..63 (K: 0..31, V: 32..63)
        int c4  = c - row * ROWC;                // 0..14
        int g0  = min(max(ws + c4 * 4, 0), NPOS - 4);
        const float* src = (row < HD)
            ? kg + (size_t)row * NPOS + g0
            : vg + (size_t)(row - HD) * NPOS + g0;
        gload16(src, buf + c * 4);               // LDS dest linear in lane
    }
}

__global__ __launch_bounds__(64) void dilate_attn_kernel(
    const float* __restrict__ q,
    const float* __restrict__ k,
    const float* __restrict__ v,
    float* __restrict__ out)
{
    // Private double-buffered staging: 2 x (K rows + V rows) = 30720 B.
    // One wave owns both buffers -> ZERO barriers in the whole kernel.
    __shared__ float kv[2][2 * HD * RS];

    // ---- XCD-aware remap: all 32 blocks of a bh land on ONE XCD, ----------
    // consecutive tile-groups consecutive in dispatch (halo lines L2-hot).
    const int id  = blockIdx.x;                  // 0..2047
    const int xcd = id & (NXCD - 1);
    const int seq = id >> 3;                     // 0..255
    const int tg  = seq & (NBLK - 1);            // 0..31: tile group
    const int bh  = ((seq >> 5) << 3) | xcd;     // 0..63
    const int t0  = tg * TPB;                    // first tile of this wave

    const size_t cb = (size_t)bh * HD * NPOS;
    const float* qg = q + cb;
    const float* kg = k + cb;
    const float* vg = v + cb;

    const int tid = threadIdx.x;                 // 0..63 (one wave)
    const int cs  = tid & (CSPL - 1);            // channel octet slot
    const int lg  = tid >> 3;                    // 0..7: token group
    const int b   = bh >> 4;
    const int hh  = bh & (NH - 1);

    const float scale = 0.17677669529663687f;    // 32^-0.5

    float4 qv[2][CPT];                           // static-indexed under unroll

    // ---- prologue: issue tile t0's q(4) + KV(15); nothing waits yet --------
#pragma unroll
    for (int i = 0; i < CPT; ++i)
        qv[0][i] = *(const float4*)(qg + (size_t)(cs * CPT + i) * NPOS
                                    + t0 * TILE + lg * TPT);
    asm volatile("" ::: "memory");
    stage_kv(kg, vg, t0 * TILE - PAD, tid, kv[0]);
    asm volatile("" ::: "memory");

#pragma unroll
    for (int t = 0; t < TPB; ++t) {
        const int tile = t0 + t;
        const int n0   = tile * TILE + lg * TPT; // first token this thread owns
        float* buf = kv[t & 1];                  // compile-time after unroll

        // ---- issue tile t+1's q+KV first: keeps 19 loads in flight --------
        if (t < TPB - 1) {
#pragma unroll
            for (int i = 0; i < CPT; ++i)
                qv[(t + 1) & 1][i] =
                    *(const float4*)(qg + (size_t)(cs * CPT + i) * NPOS
                                     + (tile + 1) * TILE + lg * TPT);
            asm volatile("" ::: "memory");
            stage_kv(kg, vg, (tile + 1) * TILE - PAD, tid, kv[(t + 1) & 1]);
            asm volatile("" ::: "memory");
        }

        // ---- counted wait: all of stage(t) retired (in-order vmcnt) -------
        // outstanding after = [stores(t-1):4 if t>=1] + [stage(t+1):19 if t<TPB-1]
        if (t == 0)           asm volatile("s_waitcnt vmcnt(19)" ::: "memory");
        else if (t < TPB - 1) asm volatile("s_waitcnt vmcnt(23)" ::: "memory");
        else                  asm volatile("s_waitcnt vmcnt(4)"  ::: "memory");

        // ---- Pass 1: scores from private LDS K ----------------------------
        float s[TPT][KW];
#pragma unroll
        for (int tt = 0; tt < TPT; ++tt)
#pragma unroll
            for (int j = 0; j < KW; ++j) s[tt][j] = 0.0f;

#pragma unroll
        for (int i = 0; i < CPT; ++i) {
            int row = cs * CPT + i;
            float w[WSPAN];
            const float4* wp = (const float4*)&buf[row * RS + lg * TPT];
#pragma unroll
            for (int u = 0; u < WCHK; ++u) {
                float4 x = wp[u];
                w[4*u] = x.x; w[4*u+1] = x.y; w[4*u+2] = x.z; w[4*u+3] = x.w;
            }
            float qt[TPT] = {qv[t & 1][i].x, qv[t & 1][i].y,
                             qv[t & 1][i].z, qv[t & 1][i].w};
#pragma unroll
            for (int tt = 0; tt < TPT; ++tt)
#pragma unroll
                for (int j = 0; j < KW; ++j)
                    s[tt][j] = fmaf(qt[tt], w[tt + 3*j], s[tt][j]);
        }

        // Reduce partials across the 8 channel-split lanes (DPP, no DS ops)
#pragma unroll
        for (int tt = 0; tt < TPT; ++tt)
#pragma unroll
            for (int j = 0; j < KW; ++j)
                s[tt][j] = dpp_sum8(s[tt][j]);

        // ---- Softmax (tap-mask only for tiles 0 / 127; wave-uniform) ------
        const bool masked = (tile == 0) || (tile == NTILES - 1);
        if (!masked) {
#pragma unroll
            for (int tt = 0; tt < TPT; ++tt) {
                float m = -INFINITY;
#pragma unroll
                for (int j = 0; j < KW; ++j) {
                    float x = s[tt][j] * scale;
                    s[tt][j] = x;
                    m = fmaxf(m, x);
                }
                float sum = 0.0f;
#pragma unroll
                for (int j = 0; j < KW; ++j) {
                    float e = __expf(s[tt][j] - m);
                    s[tt][j] = e;
                    sum += e;
                }
                float inv = 1.0f / sum;
#pragma unroll
                for (int j = 0; j < KW; ++j) s[tt][j] *= inv;
            }
        } else {
            // invalid taps: logit exactly 0 (Unfold zero-padding), prob zeroed
#pragma unroll
            for (int tt = 0; tt < TPT; ++tt) {
                float vm[KW];
                float m = -INFINITY;
#pragma unroll
                for (int j = 0; j < KW; ++j) {
                    vm[j] = ((unsigned)(n0 + tt + 3*j - PAD) < NPOS) ? 1.0f : 0.0f;
                    float x = s[tt][j] * scale * vm[j];
                    s[tt][j] = x;
                    m = fmaxf(m, x);
                }
                float sum = 0.0f;
#pragma unroll
                for (int j = 0; j < KW; ++j) {
                    float e = __expf(s[tt][j] - m);
                    s[tt][j] = e;
                    sum += e;
                }
                float inv = 1.0f / sum;
#pragma unroll
                for (int j = 0; j < KW; ++j)
                    s[tt][j] *= inv * vm[j];
            }
        }

        // ---- Pass 2: output from private LDS V (already resident) --------
        float o[TPT][CPT];
#pragma unroll
        for (int tt = 0; tt < TPT; ++tt)
#pragma unroll
            for (int i = 0; i < CPT; ++i) o[tt][i] = 0.0f;

#pragma unroll
        for (int i = 0; i < CPT; ++i) {
            int row = cs * CPT + i;
            float w[WSPAN];
            const float4* wp = (const float4*)&buf[(HD + row) * RS + lg * TPT];
#pragma unroll
            for (int u = 0; u < WCHK; ++u) {
                float4 x = wp[u];
                w[4*u] = x.x; w[4*u+1] = x.y; w[4*u+2] = x.z; w[4*u+3] = x.w;
            }
#pragma unroll
            for (int tt = 0; tt < TPT; ++tt)
#pragma unroll
                for (int j = 0; j < KW; ++j)
                    o[tt][i] = fmaf(s[tt][j], w[tt + 3*j], o[tt][i]);
        }

        // ---- Store: one NT float4 per token (4 insts, tracked in vmcnt) ---
#pragma unroll
        for (int tt = 0; tt < TPT; ++tt) {
            float* op = out + ((size_t)(b * NPOS + n0 + tt)) * DCH
                        + hh * HD + cs * CPT;
            floatx4 val = {o[tt][0], o[tt][1], o[tt][2], o[tt][3]};
            __builtin_nontemporal_store(val, (floatx4*)op);
        }
        asm volatile("" ::: "memory");
    }
}

extern "C" void kernel_launch(void* const* d_in, const int* in_sizes, int n_in,
                              void* d_out, int out_size, void* d_ws, size_t ws_size,
                              hipStream_t stream) {
    const float* q = (const float*)d_in[0];
    const float* k = (const float*)d_in[1];
    const float* v = (const float*)d_in[2];
    float* out = (float*)d_out;

    const int grid = 4 * NH * NBLK;     // 64 bh * 32 = 2048 persistent 1-wave blocks
    hipLaunchKernelGGL(dilate_attn_kernel, dim3(grid), dim3(64), 0, stream,
                       q, k, v, out);
}